// Round 6
// baseline (523.791 us; speedup 1.0000x reference)
//
#include <hip/hip_runtime.h>
#include <math.h>

// LiquidNet2: B=1024, I=128, S=512, UNFOLDS=6, out v[B,S] fp32.
//
// Layout: block = postsynaptic neuron j (512 blocks), thread = batch pair
// (512 threads, b = 2*tid, 2*tid+1).  All params (A,C,Ws) for (i,j) are
// block-uniform -> scalar loads (SMEM pipe), no LDS, no gathers.
// v kept transposed vT[S][B] in ws so the i-loop reads coalesced rows.
// Unfold dependency = 6 separate launches ping-ponging vT (stream-ordered).
//
// sigmoid: s = 1/(1+2^t), t = A*v + C, A=-sigma*log2e, C=sigma*mu*log2e.
// rcp via bit-trick + 2 Newton (main pipe), exp2 on trans pipe.
// erev=+-1 folded: Ws = W*erev; num += Ws*s; den += |Ws|*s (free abs modifier).

#define B_TOT 1024
#define I_DIM 128
#define S_DIM 512
#define UNFOLDS 6
#define L2E 1.4426950408889634f

// float offsets into ws
#define OFF_RECA 0
#define OFF_RECC (OFF_RECA + S_DIM * S_DIM)
#define OFF_RECW (OFF_RECC + S_DIM * S_DIM)
#define OFF_SENA (OFF_RECW + S_DIM * S_DIM)
#define OFF_SENC (OFF_SENA + S_DIM * I_DIM)
#define OFF_SENW (OFF_SENC + S_DIM * I_DIM)
#define OFF_XT   (OFF_SENW + S_DIM * I_DIM)
#define OFF_VA   (OFF_XT + I_DIM * B_TOT)
#define OFF_VB   (OFF_VA + S_DIM * B_TOT)
#define OFF_SN   (OFF_VB + S_DIM * B_TOT)
#define OFF_SD   (OFF_SN + S_DIM * B_TOT)
// total = 3211264 floats = 12.25 MiB

__device__ __forceinline__ float rcp_nr2(float d) {
    float y = __int_as_float(0x7EF311C3 - __float_as_int(d));
    y = y * fmaf(-d, y, 2.0f);
    y = y * fmaf(-d, y, 2.0f);
    return y;
}

__device__ __forceinline__ float sigv(float a, float c, float v) {
    float t = fmaf(a, v, c);
    t = __builtin_amdgcn_fmed3f(t, -126.0f, 126.0f);   // keep exp2/rcp finite
    float e = __builtin_amdgcn_exp2f(t);
    return rcp_nr2(1.0f + e);
}

// ---------------- prep: transposes + param transform ----------------
// ranges: [0,256) rec params (512x512), [256,320) sens params (128x512),
//         [320,448) xT (1024x128 affine), [448,960) vT0 (1024x512)
__global__ __launch_bounds__(256) void prep_all(
    const float* __restrict__ inputs, const float* __restrict__ hx,
    const float* __restrict__ input_w, const float* __restrict__ input_b,
    const float* __restrict__ s_mu, const float* __restrict__ s_sigma,
    const float* __restrict__ s_W, const float* __restrict__ s_erev,
    const float* __restrict__ mu, const float* __restrict__ sigma,
    const float* __restrict__ W, const float* __restrict__ erev,
    float* __restrict__ ws)
{
    __shared__ float tA[32][33], tB[32][33], tC[32][33];
    const int bid = blockIdx.x;
    const int tx = threadIdx.x & 31, ty = threadIdx.x >> 5;   // 32 x 8

    if (bid < 320) {
        // param transform + transpose: src [i][j] row-major -> dst [j][i]
        bool rec = bid < 256;
        int b2  = rec ? bid : bid - 256;
        int tri = b2 >> 4;            // i-tile
        int tcj = b2 & 15;            // j-tile
        const float* sgp = rec ? sigma : s_sigma;
        const float* mup = rec ? mu    : s_mu;
        const float* wp  = rec ? W     : s_W;
        const float* erp = rec ? erev  : s_erev;
        #pragma unroll
        for (int rr = 0; rr < 4; ++rr) {
            int r = ty + rr * 8;                       // i in tile
            int idx = (tri * 32 + r) * S_DIM + tcj * 32 + tx;
            float sg = sgp[idx], m = mup[idx], w = wp[idx], er = erp[idx];
            tA[r][tx] = -sg * L2E;
            tB[r][tx] = sg * m * L2E;
            tC[r][tx] = w * er;                        // signed; |.| = w
        }
        __syncthreads();
        float* dA = ws + (rec ? OFF_RECA : OFF_SENA);
        float* dC = ws + (rec ? OFF_RECC : OFF_SENC);
        float* dW = ws + (rec ? OFF_RECW : OFF_SENW);
        int ld = rec ? S_DIM : I_DIM;
        #pragma unroll
        for (int rr = 0; rr < 4; ++rr) {
            int jj = ty + rr * 8;                      // j in tile
            int o = (tcj * 32 + jj) * ld + tri * 32 + tx;
            dA[o] = tA[tx][jj];
            dC[o] = tB[tx][jj];
            dW[o] = tC[tx][jj];
        }
    } else if (bid < 448) {
        // xT[i][b] = inputs[b][i]*w[i]+b[i] ; src 1024x128
        int b2 = bid - 320;
        int tbr = b2 >> 2;            // b-tile (32 of them)
        int tci = b2 & 3;             // i-tile (4 of them)
        int i = tci * 32 + tx;
        float wi = input_w[i], bi = input_b[i];
        #pragma unroll
        for (int rr = 0; rr < 4; ++rr) {
            int r = ty + rr * 8;
            tA[r][tx] = inputs[(tbr * 32 + r) * I_DIM + i] * wi + bi;
        }
        __syncthreads();
        float* xT = ws + OFF_XT;
        #pragma unroll
        for (int rr = 0; rr < 4; ++rr) {
            int ii = ty + rr * 8;
            xT[(tci * 32 + ii) * B_TOT + tbr * 32 + tx] = tA[tx][ii];
        }
    } else {
        // vT0[j][b] = hx[b][j] ; src 1024x512
        int b2 = bid - 448;
        int tbr = b2 >> 4;            // b-tile (32)
        int tcj = b2 & 15;            // j-tile (16)
        #pragma unroll
        for (int rr = 0; rr < 4; ++rr) {
            int r = ty + rr * 8;
            tA[r][tx] = hx[(tbr * 32 + r) * S_DIM + tcj * 32 + tx];
        }
        __syncthreads();
        float* vA = ws + OFF_VA;
        #pragma unroll
        for (int rr = 0; rr < 4; ++rr) {
            int jj = ty + rr * 8;
            vA[(tcj * 32 + jj) * B_TOT + tbr * 32 + tx] = tA[tx][jj];
        }
    }
}

// ---------------- column reduction core ----------------
__device__ __forceinline__ void col_reduce(
    const float* __restrict__ pA, const float* __restrict__ pC,
    const float* __restrict__ pW, const float* __restrict__ vsrc,
    int nd, int tb, float& n0, float& n1, float& d0, float& d1)
{
    #pragma unroll 8
    for (int i = 0; i < nd; ++i) {
        float a = pA[i], c = pC[i], w = pW[i];     // block-uniform -> s_load
        const float* p = vsrc + i * B_TOT;         // uniform base walk
        float2 v = *(const float2*)&p[tb];         // coalesced dwordx2
        float s0 = sigv(a, c, v.x);
        float s1 = sigv(a, c, v.y);
        n0 = fmaf(w, s0, n0);
        d0 = fmaf(fabsf(w), s0, d0);               // abs = free input modifier
        n1 = fmaf(w, s1, n1);
        d1 = fmaf(fabsf(w), s1, d1);
    }
}

// ---------------- sensory (once) ----------------
__global__ __launch_bounds__(512, 4) void sensory_kernel(float* __restrict__ ws)
{
    const int j = blockIdx.x;
    const int tb = threadIdx.x * 2;
    const float* pA = ws + OFF_SENA + j * I_DIM;
    const float* pC = ws + OFF_SENC + j * I_DIM;
    const float* pW = ws + OFF_SENW + j * I_DIM;
    float n0 = 0.f, n1 = 0.f, d0 = 0.f, d1 = 0.f;
    col_reduce(pA, pC, pW, ws + OFF_XT, I_DIM, tb, n0, n1, d0, d1);
    *(float2*)&ws[OFF_SN + j * B_TOT + tb] = make_float2(n0, n1);
    *(float2*)&ws[OFF_SD + j * B_TOT + tb] = make_float2(d0, d1);
}

// ---------------- one unfold ----------------
__global__ __launch_bounds__(512, 4) void unfold_kernel(
    const float* __restrict__ ws, const float* __restrict__ vsrc,
    float* __restrict__ vdst,
    const float* __restrict__ gleak, const float* __restrict__ vleak,
    const float* __restrict__ cm_t,
    float* __restrict__ out, int write_out)
{
    const int j = blockIdx.x;
    const int tb = threadIdx.x * 2;
    const float* pA = ws + OFF_RECA + j * S_DIM;
    const float* pC = ws + OFF_RECC + j * S_DIM;
    const float* pW = ws + OFF_RECW + j * S_DIM;
    float n0 = 0.f, n1 = 0.f, d0 = 0.f, d1 = 0.f;
    col_reduce(pA, pC, pW, vsrc, S_DIM, tb, n0, n1, d0, d1);

    float2 sn = *(const float2*)&ws[OFF_SN + j * B_TOT + tb];
    float2 sd = *(const float2*)&ws[OFF_SD + j * B_TOT + tb];
    float2 vo = *(const float2*)&vsrc[j * B_TOT + tb];
    float gl = gleak[j], vl = vleak[j], cm = cm_t[j];
    float glvl = gl * vl, cg = cm + gl;

    float r0 = (fmaf(cm, vo.x, glvl) + n0 + sn.x) / (cg + d0 + sd.x);
    float r1 = (fmaf(cm, vo.y, glvl) + n1 + sn.y) / (cg + d1 + sd.y);

    if (write_out) {
        out[tb * S_DIM + j] = r0;
        out[(tb + 1) * S_DIM + j] = r1;
    } else {
        *(float2*)&vdst[j * B_TOT + tb] = make_float2(r0, r1);
    }
}

extern "C" void kernel_launch(void* const* d_in, const int* in_sizes, int n_in,
                              void* d_out, int out_size, void* d_ws, size_t ws_size,
                              hipStream_t stream) {
    const float* inputs   = (const float*)d_in[0];
    const float* hx       = (const float*)d_in[1];
    const float* input_w  = (const float*)d_in[2];
    const float* input_b  = (const float*)d_in[3];
    const float* s_mu     = (const float*)d_in[4];
    const float* s_sigma  = (const float*)d_in[5];
    const float* s_W      = (const float*)d_in[6];
    const float* s_erev   = (const float*)d_in[7];
    const float* mu       = (const float*)d_in[8];
    const float* sigma    = (const float*)d_in[9];
    const float* W        = (const float*)d_in[10];
    const float* erev     = (const float*)d_in[11];
    const float* vleak    = (const float*)d_in[12];
    const float* gleak    = (const float*)d_in[13];
    const float* cm_t     = (const float*)d_in[14];
    float* out = (float*)d_out;
    float* ws  = (float*)d_ws;

    prep_all<<<960, 256, 0, stream>>>(inputs, hx, input_w, input_b,
                                      s_mu, s_sigma, s_W, s_erev,
                                      mu, sigma, W, erev, ws);

    sensory_kernel<<<S_DIM, 512, 0, stream>>>(ws);

    float* vA = ws + OFF_VA;
    float* vB = ws + OFF_VB;
    for (int u = 0; u < UNFOLDS; ++u) {
        const float* src = (u & 1) ? vB : vA;
        float* dst       = (u & 1) ? vA : vB;
        int last = (u == UNFOLDS - 1);
        unfold_kernel<<<S_DIM, 512, 0, stream>>>(
            ws, src, dst, gleak, vleak, cm_t, out, last);
    }
}

// Round 7
// 434.380 us; speedup vs baseline: 1.2058x; 1.2058x over previous
//
#include <hip/hip_runtime.h>
#include <math.h>

// LiquidNet2: B=1024, I=128, S=512, UNFOLDS=6, out v[B,S] fp32.
//
// Block = postsynaptic neuron j (512 blocks), thread = batch PAIR (512 thr).
// The pair is computed with packed-f32 VALU (v_pk_fma_f32 / v_pk_add_f32,
// VOP3P op_sel broadcasts) + hardware v_exp_f32 / v_rcp_f32:
//   t(pair)  = pk_fma(AC, v, AC)  op_sel broadcast: A*v + C for both halves
//   e0,e1    = v_exp_f32 (t)            (2^t; overflow->inf is benign)
//   r(pair)  = pk_add(e, 1)
//   s0,s1    = v_rcp_f32 (r)            (rcp(inf)=0 == correct saturation)
//   n(pair) += Wn*s ; d(pair) += Wp*s   (pk_fma, op_sel broadcast of Wn/Wp)
// Params as float4 records (A,C,Wn,Wp) in [j][i] order -> one dwordx4
// broadcast load per i per wave.  A=-sigma*log2e, C=sigma*mu*log2e,
// Wn=W*erev, Wp=W.  v transposed vT[S][B]; 6 stream-ordered unfold launches.

#define B_TOT 1024
#define I_DIM 128
#define S_DIM 512
#define UNFOLDS 6
#define L2E 1.4426950408889634f

typedef float v2f __attribute__((ext_vector_type(2)));

// ---- ws layout (floats); vB overlays sensQ+xT (dead after sensory) ----
#define OFF_RECQ 0                                   // 512*512*4  = 4 MiB
#define OFF_VA   (OFF_RECQ + S_DIM * S_DIM * 4)      // 512*1024   = 2 MiB
#define OFF_SN   (OFF_VA + S_DIM * B_TOT)            // 2 MiB
#define OFF_SD   (OFF_SN + S_DIM * B_TOT)            // 2 MiB
#define OFF_SENQ (OFF_SD + S_DIM * B_TOT)            // 512*128*4  = 1 MiB
#define OFF_XT   (OFF_SENQ + S_DIM * I_DIM * 4)      // 128*1024   = 0.5 MiB
#define OFF_VB   OFF_SENQ                            // 2 MiB overlay
// total = 12.0 MiB

// ---------------- prep: param transform + transposes ----------------
__global__ __launch_bounds__(256) void prep_all(
    const float* __restrict__ inputs, const float* __restrict__ hx,
    const float* __restrict__ input_w, const float* __restrict__ input_b,
    const float* __restrict__ s_mu, const float* __restrict__ s_sigma,
    const float* __restrict__ s_W, const float* __restrict__ s_erev,
    const float* __restrict__ mu, const float* __restrict__ sigma,
    const float* __restrict__ W, const float* __restrict__ erev,
    float* __restrict__ ws)
{
    __shared__ float tA[32][33], tB[32][33], tC[32][33];
    const int bid = blockIdx.x;
    const int tx = threadIdx.x & 31, ty = threadIdx.x >> 5;   // 32 x 8

    if (bid < 320) {
        // params: src [i][j] row-major -> dst [j][i] float4 (A,C,Wn,|Wn|)
        bool rec = bid < 256;
        int b2  = rec ? bid : bid - 256;
        int tri = b2 >> 4;            // i-tile
        int tcj = b2 & 15;            // j-tile
        const float* sgp = rec ? sigma : s_sigma;
        const float* mup = rec ? mu    : s_mu;
        const float* wp  = rec ? W     : s_W;
        const float* erp = rec ? erev  : s_erev;
        #pragma unroll
        for (int rr = 0; rr < 4; ++rr) {
            int r = ty + rr * 8;
            int idx = (tri * 32 + r) * S_DIM + tcj * 32 + tx;
            float sg = sgp[idx], m = mup[idx], w = wp[idx], er = erp[idx];
            tA[r][tx] = -sg * L2E;
            tB[r][tx] = sg * m * L2E;
            tC[r][tx] = w * er;
        }
        __syncthreads();
        float4* dst = (float4*)(ws + (rec ? OFF_RECQ : OFF_SENQ));
        int ld = rec ? S_DIM : I_DIM;
        #pragma unroll
        for (int rr = 0; rr < 4; ++rr) {
            int jj = ty + rr * 8;
            float wn = tC[tx][jj];
            dst[(tcj * 32 + jj) * ld + tri * 32 + tx] =
                make_float4(tA[tx][jj], tB[tx][jj], wn, fabsf(wn));
        }
    } else if (bid < 448) {
        // xT[i][b] = inputs[b][i]*w[i]+b[i]
        int b2 = bid - 320;
        int tbr = b2 >> 2, tci = b2 & 3;
        int i = tci * 32 + tx;
        float wi = input_w[i], bi = input_b[i];
        #pragma unroll
        for (int rr = 0; rr < 4; ++rr) {
            int r = ty + rr * 8;
            tA[r][tx] = inputs[(tbr * 32 + r) * I_DIM + i] * wi + bi;
        }
        __syncthreads();
        float* xT = ws + OFF_XT;
        #pragma unroll
        for (int rr = 0; rr < 4; ++rr) {
            int ii = ty + rr * 8;
            xT[(tci * 32 + ii) * B_TOT + tbr * 32 + tx] = tA[tx][ii];
        }
    } else {
        // vA[j][b] = hx[b][j]
        int b2 = bid - 448;
        int tbr = b2 >> 4, tcj = b2 & 15;
        #pragma unroll
        for (int rr = 0; rr < 4; ++rr) {
            int r = ty + rr * 8;
            tA[r][tx] = hx[(tbr * 32 + r) * S_DIM + tcj * 32 + tx];
        }
        __syncthreads();
        float* vA = ws + OFF_VA;
        #pragma unroll
        for (int rr = 0; rr < 4; ++rr) {
            int jj = ty + rr * 8;
            vA[(tcj * 32 + jj) * B_TOT + tbr * 32 + tx] = tA[tx][jj];
        }
    }
}

// ---------------- packed sigmoid-accumulate step ----------------
__device__ __forceinline__ void sig_step(v2f ac, v2f ww, v2f v, v2f one,
                                         v2f& n, v2f& d)
{
    v2f t;
    // t.lo = ac.lo*v.lo + ac.hi ; t.hi = ac.lo*v.hi + ac.hi
    asm("v_pk_fma_f32 %0, %1, %2, %1 op_sel:[0,0,1] op_sel_hi:[0,1,1]"
        : "=v"(t) : "v"(ac), "v"(v));
    float e0, e1;
    asm("v_exp_f32 %0, %1" : "=v"(e0) : "v"(t.x));
    asm("v_exp_f32 %0, %1" : "=v"(e1) : "v"(t.y));
    v2f e; e.x = e0; e.y = e1;
    v2f r;
    asm("v_pk_add_f32 %0, %1, %2" : "=v"(r) : "v"(e), "v"(one));
    float s0, s1;
    asm("v_rcp_f32 %0, %1" : "=v"(s0) : "v"(r.x));
    asm("v_rcp_f32 %0, %1" : "=v"(s1) : "v"(r.y));
    v2f s; s.x = s0; s.y = s1;
    // n += Wn*s (broadcast ww.lo) ; d += Wp*s (broadcast ww.hi)
    asm("v_pk_fma_f32 %0, %1, %2, %0 op_sel:[0,0,0] op_sel_hi:[0,1,1]"
        : "+v"(n) : "v"(ww), "v"(s));
    asm("v_pk_fma_f32 %0, %1, %2, %0 op_sel:[1,0,0] op_sel_hi:[1,1,1]"
        : "+v"(d) : "v"(ww), "v"(s));
}

__device__ __forceinline__ void col_reduce_pk(
    const float4* __restrict__ qp,   // [nd] records for this j
    const float* __restrict__ vsrc,  // [nd][B_TOT]
    int nd, int tb, v2f one, v2f& n, v2f& d)
{
    #pragma unroll 8
    for (int i = 0; i < nd; ++i) {
        float4 q = qp[i];                         // broadcast dwordx4
        v2f ac; ac.x = q.x; ac.y = q.y;
        v2f ww; ww.x = q.z; ww.y = q.w;
        v2f v = *(const v2f*)(vsrc + (size_t)i * B_TOT + tb);
        sig_step(ac, ww, v, one, n, d);
    }
}

// ---------------- sensory (once) ----------------
__global__ __launch_bounds__(512, 4) void sensory_kernel(float* __restrict__ ws)
{
    const int j = blockIdx.x;
    const int tb = threadIdx.x * 2;
    v2f one; one.x = 1.0f; one.y = 1.0f;
    v2f n; n.x = 0.f; n.y = 0.f;
    v2f d; d.x = 0.f; d.y = 0.f;
    col_reduce_pk((const float4*)(ws + OFF_SENQ) + j * I_DIM,
                  ws + OFF_XT, I_DIM, tb, one, n, d);
    *(v2f*)&ws[OFF_SN + j * B_TOT + tb] = n;
    *(v2f*)&ws[OFF_SD + j * B_TOT + tb] = d;
}

// ---------------- one unfold ----------------
__global__ __launch_bounds__(512, 4) void unfold_kernel(
    const float* __restrict__ ws, const float* __restrict__ vsrc,
    float* __restrict__ vdst,
    const float* __restrict__ gleak, const float* __restrict__ vleak,
    const float* __restrict__ cm_t,
    float* __restrict__ out, int write_out)
{
    const int j = blockIdx.x;
    const int tb = threadIdx.x * 2;
    v2f one; one.x = 1.0f; one.y = 1.0f;
    v2f n = *(const v2f*)&ws[OFF_SN + j * B_TOT + tb];   // init with sensory
    v2f d = *(const v2f*)&ws[OFF_SD + j * B_TOT + tb];
    col_reduce_pk((const float4*)(ws + OFF_RECQ) + j * S_DIM,
                  vsrc, S_DIM, tb, one, n, d);

    v2f vo = *(const v2f*)&vsrc[j * B_TOT + tb];
    float gl = gleak[j], vl = vleak[j], cm = cm_t[j];
    float glvl = gl * vl, cg = cm + gl;

    float r0 = (fmaf(cm, vo.x, glvl) + n.x) / (cg + d.x);
    float r1 = (fmaf(cm, vo.y, glvl) + n.y) / (cg + d.y);

    if (write_out) {
        out[tb * S_DIM + j] = r0;
        out[(tb + 1) * S_DIM + j] = r1;
    } else {
        v2f rr; rr.x = r0; rr.y = r1;
        *(v2f*)&vdst[j * B_TOT + tb] = rr;
    }
}

extern "C" void kernel_launch(void* const* d_in, const int* in_sizes, int n_in,
                              void* d_out, int out_size, void* d_ws, size_t ws_size,
                              hipStream_t stream) {
    const float* inputs   = (const float*)d_in[0];
    const float* hx       = (const float*)d_in[1];
    const float* input_w  = (const float*)d_in[2];
    const float* input_b  = (const float*)d_in[3];
    const float* s_mu     = (const float*)d_in[4];
    const float* s_sigma  = (const float*)d_in[5];
    const float* s_W      = (const float*)d_in[6];
    const float* s_erev   = (const float*)d_in[7];
    const float* mu       = (const float*)d_in[8];
    const float* sigma    = (const float*)d_in[9];
    const float* W        = (const float*)d_in[10];
    const float* erev     = (const float*)d_in[11];
    const float* vleak    = (const float*)d_in[12];
    const float* gleak    = (const float*)d_in[13];
    const float* cm_t     = (const float*)d_in[14];
    float* out = (float*)d_out;
    float* ws  = (float*)d_ws;

    prep_all<<<960, 256, 0, stream>>>(inputs, hx, input_w, input_b,
                                      s_mu, s_sigma, s_W, s_erev,
                                      mu, sigma, W, erev, ws);

    sensory_kernel<<<S_DIM, 512, 0, stream>>>(ws);

    float* vA = ws + OFF_VA;
    float* vB = ws + OFF_VB;
    for (int u = 0; u < UNFOLDS; ++u) {
        const float* src = (u & 1) ? vB : vA;
        float* dst       = (u & 1) ? vA : vB;
        int last = (u == UNFOLDS - 1);
        unfold_kernel<<<S_DIM, 512, 0, stream>>>(
            ws, src, dst, gleak, vleak, cm_t, out, last);
    }
}